// Round 7
// baseline (534.921 us; speedup 1.0000x reference)
//
#include <hip/hip_runtime.h>

#define BB 32
#define NN 1024
#define HH 512
#define NS 1023   // S length per row

typedef unsigned short u16;
typedef unsigned int   u32;
typedef __attribute__((ext_vector_type(8))) short bf16x8;
typedef __attribute__((ext_vector_type(4))) float f32x4;

__device__ __forceinline__ float bf2f(u16 h) {
  union { u32 u; float f; } c; c.u = ((u32)h) << 16; return c.f;
}
__device__ __forceinline__ u16 f2bf(float f) {
  union { float f; u32 u; } c; c.f = f;
  u32 u = c.u;
  return (u16)((u + 0x7fffu + ((u >> 16) & 1u)) >> 16);
}
// split x = hi + lo (each bf16); residual ~2^-18 relative
__device__ __forceinline__ void split_bf(float x, u16& hi, u16& lo) {
  hi = f2bf(x);
  lo = f2bf(x - bf2f(hi));
}

// ---------------------------------------------------------------- prep A
// normalize seg rows, split to bf16 hi/lo planes stored in d_out
__global__ __launch_bounds__(64) void k_prep_a(const float* __restrict__ seg,
                                               u16* __restrict__ ahi,
                                               u16* __restrict__ alo) {
  int row = blockIdx.x, lane = threadIdx.x;
  const float4* p = (const float4*)(seg + ((size_t)row << 9) + lane * 8);
  float4 a = p[0], b = p[1];
  float v[8] = {a.x, a.y, a.z, a.w, b.x, b.y, b.z, b.w};
  float s = 0.f;
#pragma unroll
  for (int i = 0; i < 8; ++i) s += v[i] * v[i];
#pragma unroll
  for (int m = 32; m; m >>= 1) s += __shfl_xor(s, m, 64);
  float nrm = sqrtf(s);
  u16 h[8], l[8];
#pragma unroll
  for (int i = 0; i < 8; ++i) split_bf(v[i] / nrm, h[i], l[i]);
  size_t off = ((size_t)row << 9) + lane * 8;
  *(uint4*)(ahi + off) = make_uint4(h[0] | (h[1] << 16), h[2] | (h[3] << 16),
                                    h[4] | (h[5] << 16), h[6] | (h[7] << 16));
  *(uint4*)(alo + off) = make_uint4(l[0] | (l[1] << 16), l[2] | (l[3] << 16),
                                    l[4] | (l[5] << 16), l[6] | (l[7] << 16));
}

// ---------------------------------------------------------------- transpose-split
// src (K x N, row-major) -> dh[n][k] (+ dl if dl != nullptr), bf16.
__global__ __launch_bounds__(256) void k_tr(const float* __restrict__ src,
                                            u16* __restrict__ dh,
                                            u16* __restrict__ dl,
                                            int K, int N) {
  __shared__ u16 Th[64 * 66], Tl[64 * 66];
  int nb = blockIdx.x * 64, kb = blockIdx.y * 64;
  int tid = threadIdx.x;
#pragma unroll
  for (int i = 0; i < 16; ++i) {
    int e = tid + i * 256;
    int r = e >> 6, c = e & 63;
    float v = src[(size_t)(kb + r) * N + nb + c];
    u16 hi, lo; split_bf(v, hi, lo);
    Th[c * 66 + r] = hi;
    Tl[c * 66 + r] = lo;
  }
  __syncthreads();
#pragma unroll
  for (int i = 0; i < 16; ++i) {
    int e = tid + i * 256;
    int n = e >> 6, k = e & 63;
    dh[(size_t)(nb + n) * K + kb + k] = Th[n * 66 + k];
    if (dl) dl[(size_t)(nb + n) * K + kb + k] = Tl[n * 66 + k];
  }
}

// ---------------------------------------------------------------- S-GEMM (MFMA)
// hidden = relu(cat(A[n],A[n+1]) @ W1 + b1); Spart[nblk] = hidden_strip . W2
// W fragments straight from global (L2-resident) -> registers; only the 8KB
// A tile goes through LDS, double-buffered. block 64m x 256n, 4 waves 64x64.
__global__ __launch_bounds__(256) void k_sgemm(const u16* __restrict__ ahi,
                                               const u16* __restrict__ alo,
                                               const u16* __restrict__ w1h,
                                               const u16* __restrict__ w1l,
                                               const float* __restrict__ b1,
                                               const float* __restrict__ W2,
                                               float* __restrict__ Spart) {
  __shared__ u16 Ah[2][64 * 32], Al_[2][64 * 32];  // [buf][m*32+k], 64B rows
  __shared__ float red[4][64];

  int tid = threadIdx.x;
  int wave = tid >> 6, lane = tid & 63, quad = lane >> 4, l15 = lane & 15;
  int b = blockIdx.z, mblk = blockIdx.y, nblk = blockIdx.x;
  int rowbase = b * NN + mblk * 64;
  int ncol0 = nblk * 256;

  int m_st = tid >> 2, ch_st = tid & 3;   // staging: 16B per thread per plane

  f32x4 acc[4][4];
#pragma unroll
  for (int mi = 0; mi < 4; ++mi)
#pragma unroll
    for (int ni = 0; ni < 4; ++ni) acc[mi][ni] = (f32x4){0.f, 0.f, 0.f, 0.f};

  // prologue: stage ks=0 into buf 0
  {
    int grow = rowbase + m_st; if (grow > 32767) grow = 32767;
    size_t g = ((size_t)grow << 9) + ch_st * 8;
    *(uint4*)&Ah [0][m_st * 32 + ch_st * 8] = *(const uint4*)(ahi + g);
    *(uint4*)&Al_[0][m_st * 32 + ch_st * 8] = *(const uint4*)(alo + g);
  }

  for (int ks = 0; ks < 32; ++ks) {
    int bb = ks & 1;
    __syncthreads();                       // buf[bb] ready
    bool have = (ks + 1) < 32;
    uint4 nh, nl;
    if (have) {                            // issue next A loads early
      int k0n = (ks + 1) * 32, halfn = k0n >> 9, cbn = k0n & 511;
      int grow = rowbase + m_st + halfn; if (grow > 32767) grow = 32767;
      size_t g = ((size_t)grow << 9) + cbn + ch_st * 8;
      nh = *(const uint4*)(ahi + g);
      nl = *(const uint4*)(alo + g);
    }
    int k0 = ks * 32;
    // W fragments from global (pipelined across barriers by HW)
    const u16* wbh = w1h + (size_t)(ncol0 + wave * 64 + l15) * 1024 + k0 + quad * 8;
    const u16* wbl = w1l + (size_t)(ncol0 + wave * 64 + l15) * 1024 + k0 + quad * 8;
    bf16x8 bh[4], bl[4];
#pragma unroll
    for (int ni = 0; ni < 4; ++ni) {
      bh[ni] = *(const bf16x8*)(wbh + (size_t)ni * 16 * 1024);
      bl[ni] = *(const bf16x8*)(wbl + (size_t)ni * 16 * 1024);
    }
    bf16x8 a_h[4], a_l[4];
#pragma unroll
    for (int mi = 0; mi < 4; ++mi) {
      int off = (mi * 16 + l15) * 32 + quad * 8;
      a_h[mi] = *(const bf16x8*)&Ah [bb][off];
      a_l[mi] = *(const bf16x8*)&Al_[bb][off];
    }
#pragma unroll
    for (int ni = 0; ni < 4; ++ni)
#pragma unroll
      for (int mi = 0; mi < 4; ++mi) {
        acc[mi][ni] = __builtin_amdgcn_mfma_f32_16x16x32_bf16(a_h[mi], bh[ni], acc[mi][ni], 0, 0, 0);
        acc[mi][ni] = __builtin_amdgcn_mfma_f32_16x16x32_bf16(a_h[mi], bl[ni], acc[mi][ni], 0, 0, 0);
        acc[mi][ni] = __builtin_amdgcn_mfma_f32_16x16x32_bf16(a_l[mi], bh[ni], acc[mi][ni], 0, 0, 0);
      }
    if (have) {                            // write next tile into other buffer
      *(uint4*)&Ah [bb ^ 1][m_st * 32 + ch_st * 8] = nh;
      *(uint4*)&Al_[bb ^ 1][m_st * 32 + ch_st * 8] = nl;
    }
  }

  // epilogue: relu(acc + b1) . W2 over this wave's 64 cols; reduce, no atomics
#pragma unroll
  for (int mi = 0; mi < 4; ++mi) {
#pragma unroll
    for (int reg = 0; reg < 4; ++reg) {
      float part = 0.f;
#pragma unroll
      for (int ni = 0; ni < 4; ++ni) {
        int n_g = ncol0 + wave * 64 + ni * 16 + l15;
        float h = acc[mi][ni][reg] + b1[n_g];
        h = h > 0.f ? h : 0.f;
        part = fmaf(h, W2[n_g], part);
      }
#pragma unroll
      for (int m = 8; m; m >>= 1) part += __shfl_xor(part, m, 64);
      if (l15 == 0) red[wave][mi * 16 + quad * 4 + reg] = part;
    }
  }
  __syncthreads();
  if (tid < 64) {
    float s = red[0][tid] + red[1][tid] + red[2][tid] + red[3][tid];
    int srow = mblk * 64 + tid;
    if (srow < NS)
      Spart[((size_t)nblk * BB + b) * NN + srow] = s;
  }
}

// ---------------------------------------------------------------- kernel 3
__global__ __launch_bounds__(256) void k_row(const float* __restrict__ S0,
                                             const float* __restrict__ S1,
                                             const float* __restrict__ mask,
                                             int* __restrict__ assign,
                                             float* __restrict__ weight,
                                             float* __restrict__ total,
                                             int* __restrict__ startn,
                                             int* __restrict__ endn) {
  int b = blockIdx.x, tid = threadIdx.x;
  __shared__ float Ssh[NS];
  __shared__ float Dsh[NS];
  __shared__ float tsh[NN];
  __shared__ float bsh[NN];
  __shared__ float totl[NN];
  __shared__ int   stl[NN];
  __shared__ int   enl[NN];
  __shared__ float red[256];

  for (int n = tid; n < NS; n += 256)
    Ssh[n] = S0[((size_t)b << 10) + n] + S1[((size_t)b << 10) + n];
  __syncthreads();

  float mn = INFINITY, mx = -INFINITY;
  for (int n = tid; n < NS; n += 256) {
    float v = Ssh[n];
    mn = fminf(mn, v); mx = fmaxf(mx, v);
  }
  red[tid] = mn; __syncthreads();
  for (int s = 128; s; s >>= 1) { if (tid < s) red[tid] = fminf(red[tid], red[tid + s]); __syncthreads(); }
  float Smin = red[0]; __syncthreads();
  red[tid] = mx; __syncthreads();
  for (int s = 128; s; s >>= 1) { if (tid < s) red[tid] = fmaxf(red[tid], red[tid + s]); __syncthreads(); }
  float Smax = red[0]; __syncthreads();

  for (int n = tid; n < NS; n += 256)
    Dsh[n] = 1.0f - (Ssh[n] - Smin) / (Smax - Smin);
  __syncthreads();

  for (int n = tid; n < NN; n += 256) {
    float P;
    if (n >= NS) {
      P = 0.f;
    } else {
      float D = Dsh[n];
      float fo, so;
      if (n == 0)            fo = fmaxf(D - Dsh[1], 0.f);
      else if (n >= NS - 2)  fo = fmaxf(D - Dsh[n - 2], 0.f);
      else                   fo = fminf(fmaxf(D - Dsh[n - 1], 0.f),
                                        fmaxf(D - Dsh[n + 1], 0.f));
      if (n <= 1)            so = fmaxf(D - Dsh[n + 2], 0.f);
      else if (n >= NS - 2)  so = 0.f;
      else                   so = fminf(fmaxf(D - Dsh[n - 2], 0.f),
                                        fmaxf(D - Dsh[n + 2], 0.f));
      P = fminf(fmaxf(fmaxf(fo, so) - 0.05f, 0.f), fo);
    }
    float m = mask[((size_t)b << 10) + n];
    P = P + (m - 1.0f);
    P = P > 0.f ? P : 0.f;
    float bs = tanhf(10.0f * P);
    float bh = tanhf(100000.0f * P);
    tsh[n] = bs + (bh - bs);
  }
  __syncthreads();

  if (tid == 0) {
    float acc = 0.f;
    for (int n = 0; n < NN; n += 8) {
      float t0 = tsh[n + 0], t1 = tsh[n + 1], t2 = tsh[n + 2], t3 = tsh[n + 3];
      float t4 = tsh[n + 4], t5 = tsh[n + 5], t6 = tsh[n + 6], t7 = tsh[n + 7];
      acc += t0; bsh[n + 0] = acc; acc += t1; bsh[n + 1] = acc;
      acc += t2; bsh[n + 2] = acc; acc += t3; bsh[n + 3] = acc;
      acc += t4; bsh[n + 4] = acc; acc += t5; bsh[n + 5] = acc;
      acc += t6; bsh[n + 6] = acc; acc += t7; bsh[n + 7] = acc;
    }
  }
  __syncthreads();

  float add1 = (bsh[0] == 0.0f) ? 1.0f : 0.0f;
  int   num  = (int)(bsh[NN - 1] + add1) + 1;

  for (int mi = tid; mi < NN; mi += 256) { totl[mi] = 0.f; stl[mi] = 1 << 30; enl[mi] = -1; }
  __syncthreads();

  for (int n = tid; n < NN; n += 256) {
    float bv = bsh[n] + add1;
    float kf = rintf(bv);
    int   k  = (int)kf;
    int   a  = -1; float w = 0.f;
    if (k >= 1 && k <= num && k <= NN) {
      float v = fabsf(kf - bv);
      w = 1.0f - tanhf(100000.0f * v);
      if (w > 0.f) {
        a = k - 1;
        atomicAdd(&totl[a], w);
        atomicMin(&stl[a], n);
        atomicMax(&enl[a], n);
      } else {
        a = -1; w = 0.f;
      }
    }
    assign[((size_t)b << 10) + n] = a;
    weight[((size_t)b << 10) + n] = w;
  }
  __syncthreads();
  for (int mi = tid; mi < NN; mi += 256) {
    total [((size_t)b << 10) + mi] = totl[mi];
    startn[((size_t)b << 10) + mi] = stl[mi];
    endn  [((size_t)b << 10) + mi] = enl[mi];
  }
}

// ---------------------------------------------------------------- kernel 4
__global__ __launch_bounds__(64) void k_pool(const float* __restrict__ seg,
                                             const int* __restrict__ assign,
                                             const float* __restrict__ weight,
                                             const float* __restrict__ total,
                                             const int* __restrict__ startn,
                                             const int* __restrict__ endn,
                                             float* __restrict__ wrep) {
  int bm = blockIdx.x;
  int b  = bm >> 10, m = bm & 1023;
  int lane = threadIdx.x;
  float acc[8] = {0.f, 0.f, 0.f, 0.f, 0.f, 0.f, 0.f, 0.f};
  float tm = total[bm];
  if (tm > 0.f) {
    int s = startn[bm], e = endn[bm];
    for (int n = s; n <= e; ++n) {
      if (assign[((size_t)b << 10) + n] != m) continue;
      float coef = weight[((size_t)b << 10) + n] / tm;
      const float4* p = (const float4*)(seg + (((size_t)b << 10) + n) * HH + lane * 8);
      float4 x = p[0], y = p[1];
      acc[0] = fmaf(coef, x.x, acc[0]); acc[1] = fmaf(coef, x.y, acc[1]);
      acc[2] = fmaf(coef, x.z, acc[2]); acc[3] = fmaf(coef, x.w, acc[3]);
      acc[4] = fmaf(coef, y.x, acc[4]); acc[5] = fmaf(coef, y.y, acc[5]);
      acc[6] = fmaf(coef, y.z, acc[6]); acc[7] = fmaf(coef, y.w, acc[7]);
    }
  }
  float4* dst = (float4*)(wrep + (size_t)bm * HH + lane * 8);
  dst[0] = make_float4(acc[0], acc[1], acc[2], acc[3]);
  dst[1] = make_float4(acc[4], acc[5], acc[6], acc[7]);
}

// ---------------------------------------------------------------- out MLP (MFMA bf16)
// W fragments from global; Hid in LDS; phase 2 barrier-free.
// block 64m x 512n; 8 waves as 2m x 4n, wave tile 32m x 128n.
__global__ __launch_bounds__(512) void k_out(const u16* __restrict__ we1t,
                                             const u16* __restrict__ we2t,
                                             const float* __restrict__ be1,
                                             const float* __restrict__ be2,
                                             float* __restrict__ io) {
  __shared__ u16 Hid[64 * 520];      // hidden bf16 [m][k] stride 520
  __shared__ u16 Ast[2][64 * 32];    // double-buffered A staging (bf16)

  int tid = threadIdx.x;
  int wave = tid >> 6, lane = tid & 63, quad = lane >> 4, l15 = lane & 15;
  int wm = wave >> 2, wn = wave & 3;
  int rowbase = blockIdx.x * 64;
  int m_st = tid >> 3, ch_st = tid & 7;    // stage: one float4 per thread

  f32x4 acc[2][8];
#pragma unroll
  for (int mi = 0; mi < 2; ++mi)
#pragma unroll
    for (int ni = 0; ni < 8; ++ni) acc[mi][ni] = (f32x4){0.f, 0.f, 0.f, 0.f};

  // prologue stage ks=0
  {
    float4 v = *(const float4*)(io + (size_t)(rowbase + m_st) * HH + ch_st * 4);
    u32 p0 = f2bf(v.x) | ((u32)f2bf(v.y) << 16);
    u32 p1 = f2bf(v.z) | ((u32)f2bf(v.w) << 16);
    *(uint2*)&Ast[0][m_st * 32 + ch_st * 4] = make_uint2(p0, p1);
  }

  // ---- phase 1: hidden = relu(wrep @ We1 + be1)
  for (int ks = 0; ks < 16; ++ks) {
    int bb = ks & 1;
    __syncthreads();
    bool have = (ks + 1) < 16;
    float4 nx;
    if (have)
      nx = *(const float4*)(io + (size_t)(rowbase + m_st) * HH + (ks + 1) * 32 + ch_st * 4);
    int k0 = ks * 32;
    const u16* wb = we1t + (size_t)(wn * 128 + l15) * 512 + k0 + quad * 8;
    bf16x8 bw[8];
#pragma unroll
    for (int ni = 0; ni < 8; ++ni) bw[ni] = *(const bf16x8*)(wb + (size_t)ni * 16 * 512);
    bf16x8 a[2];
#pragma unroll
    for (int mi = 0; mi < 2; ++mi)
      a[mi] = *(const bf16x8*)&Ast[bb][(wm * 32 + mi * 16 + l15) * 32 + quad * 8];
#pragma unroll
    for (int ni = 0; ni < 8; ++ni)
#pragma unroll
      for (int mi = 0; mi < 2; ++mi)
        acc[mi][ni] = __builtin_amdgcn_mfma_f32_16x16x32_bf16(a[mi], bw[ni], acc[mi][ni], 0, 0, 0);
    if (have) {
      u32 p0 = f2bf(nx.x) | ((u32)f2bf(nx.y) << 16);
      u32 p1 = f2bf(nx.z) | ((u32)f2bf(nx.w) << 16);
      *(uint2*)&Ast[bb ^ 1][m_st * 32 + ch_st * 4] = make_uint2(p0, p1);
    }
  }
  // hidden -> LDS (bf16)
#pragma unroll
  for (int mi = 0; mi < 2; ++mi)
#pragma unroll
    for (int ni = 0; ni < 8; ++ni)
#pragma unroll
      for (int reg = 0; reg < 4; ++reg) {
        int n_g = wn * 128 + ni * 16 + l15;
        float h = acc[mi][ni][reg] + be1[n_g];
        h = h > 0.f ? h : 0.f;
        Hid[(wm * 32 + mi * 16 + quad * 4 + reg) * 520 + n_g] = f2bf(h);
      }
  __syncthreads();

#pragma unroll
  for (int mi = 0; mi < 2; ++mi)
#pragma unroll
    for (int ni = 0; ni < 8; ++ni) acc[mi][ni] = (f32x4){0.f, 0.f, 0.f, 0.f};

  // ---- phase 2: out = hidden @ We2 + be2 (no barriers)
  for (int ks = 0; ks < 16; ++ks) {
    int k0 = ks * 32;
    const u16* wb = we2t + (size_t)(wn * 128 + l15) * 512 + k0 + quad * 8;
    bf16x8 bw[8];
#pragma unroll
    for (int ni = 0; ni < 8; ++ni) bw[ni] = *(const bf16x8*)(wb + (size_t)ni * 16 * 512);
    bf16x8 a[2];
#pragma unroll
    for (int mi = 0; mi < 2; ++mi)
      a[mi] = *(const bf16x8*)&Hid[(wm * 32 + mi * 16 + l15) * 520 + k0 + quad * 8];
#pragma unroll
    for (int ni = 0; ni < 8; ++ni)
#pragma unroll
      for (int mi = 0; mi < 2; ++mi)
        acc[mi][ni] = __builtin_amdgcn_mfma_f32_16x16x32_bf16(a[mi], bw[ni], acc[mi][ni], 0, 0, 0);
  }

  // epilogue: bias + (wrep == 0) mask, in-place f32 store (element-exclusive)
#pragma unroll
  for (int mi = 0; mi < 2; ++mi)
#pragma unroll
    for (int ni = 0; ni < 8; ++ni)
#pragma unroll
      for (int reg = 0; reg < 4; ++reg) {
        int n_g = wn * 128 + ni * 16 + l15;
        size_t row = (size_t)(rowbase + wm * 32 + mi * 16 + quad * 4 + reg);
        float o = acc[mi][ni][reg] + be2[n_g];
        float wr = io[row * HH + n_g];
        io[row * HH + n_g] = (wr == 0.f) ? 0.f : o;
      }
}

// ---------------------------------------------------------------- diag (hostcode only)
__global__ void k_diag(float* __restrict__ out, int hostcode) {
  if (hostcode != 0) out[0] = (float)hostcode;
}

// ---------------------------------------------------------------- launch
extern "C" void kernel_launch(void* const* d_in, const int* in_sizes, int n_in,
                              void* d_out, int out_size, void* d_ws, size_t ws_size,
                              hipStream_t stream) {
  const float* seg  = (const float*)d_in[0];
  const float* mask = (const float*)d_in[1];
  const float* W1   = (const float*)d_in[2];
  const float* b1   = (const float*)d_in[3];
  const float* W2   = (const float*)d_in[4];
  const float* We1  = (const float*)d_in[5];
  const float* be1  = (const float*)d_in[6];
  const float* We2  = (const float*)d_in[7];
  const float* be2  = (const float*)d_in[8];

  const size_t NROW = (size_t)BB * NN;            // 32768
  float* ws = (float*)d_ws;
  float* S0     = ws;                             // partial S, nblk=0
  float* S1     = S0 + NROW;                      // partial S, nblk=1
  int*   assign = (int*)(S1 + NROW);
  float* weight = (float*)(assign + NROW);
  float* total  = weight + NROW;
  int*   startn = (int*)(total + NROW);
  int*   endn   = startn + NROW;
  u16*   w1h    = (u16*)(endn + NROW);            // [n=512][k=1024]
  u16*   w1l    = w1h + (size_t)512 * 1024;
  u16*   we1t   = w1l + (size_t)512 * 1024;       // [n=512][k=512]
  u16*   we2t   = we1t + (size_t)512 * 512;       // end ~3.9 MB

  float* out = (float*)d_out;
  u16*   ahi = (u16*)d_out;                       // A hi plane (33.5 MB)
  u16*   alo = ahi + (size_t)NROW * HH;           // A lo plane (33.5 MB)

  int hostcode = 0;
  if (ws_size < (size_t)7 * NROW * 4 + (size_t)3 * 1024 * 1024) hostcode += 32768;
  if (out_size != 16777216) hostcode += 8192;

  k_prep_a<<<dim3(BB * NN), dim3(64), 0, stream>>>(seg, ahi, alo);
  k_tr    <<<dim3(8, 16), dim3(256), 0, stream>>>(W1, w1h, w1l, 1024, 512);
  k_tr    <<<dim3(8, 8),  dim3(256), 0, stream>>>(We1, we1t, (u16*)nullptr, 512, 512);
  k_tr    <<<dim3(8, 8),  dim3(256), 0, stream>>>(We2, we2t, (u16*)nullptr, 512, 512);
  k_sgemm <<<dim3(2, 16, BB), dim3(256), 0, stream>>>(ahi, alo, w1h, w1l, b1, W2, S0);
  k_row   <<<dim3(BB), dim3(256), 0, stream>>>(S0, S1, mask, assign, weight, total, startn, endn);
  k_pool  <<<dim3(BB * NN), dim3(64), 0, stream>>>(seg, assign, weight, total, startn, endn, out);
  k_out   <<<dim3(NROW / 64), dim3(512), 0, stream>>>(we1t, we2t, be1, be2, out);
  k_diag  <<<dim3(1), dim3(1), 0, stream>>>(out, hostcode);
}

// Round 8
// 384.934 us; speedup vs baseline: 1.3896x; 1.3896x over previous
//
#include <hip/hip_runtime.h>

#define BB 32
#define NN 1024
#define HH 512
#define NS 1023   // S length per row

typedef unsigned short u16;
typedef unsigned int   u32;
typedef __attribute__((ext_vector_type(8))) short bf16x8;
typedef __attribute__((ext_vector_type(4))) float f32x4;

__device__ __forceinline__ float bf2f(u16 h) {
  union { u32 u; float f; } c; c.u = ((u32)h) << 16; return c.f;
}
__device__ __forceinline__ u16 f2bf(float f) {
  union { float f; u32 u; } c; c.f = f;
  u32 u = c.u;
  return (u16)((u + 0x7fffu + ((u >> 16) & 1u)) >> 16);
}
// split x = hi + lo (each bf16); residual ~2^-18 relative
__device__ __forceinline__ void split_bf(float x, u16& hi, u16& lo) {
  hi = f2bf(x);
  lo = f2bf(x - bf2f(hi));
}
// async global->LDS DMA, 16 B per lane; LDS dest = wave-uniform base + lane*16
__device__ __forceinline__ void dma16(const u16* g, u16* l) {
  __builtin_amdgcn_global_load_lds(
      (const __attribute__((address_space(1))) u32*)g,
      (__attribute__((address_space(3))) u32*)l, 16, 0, 0);
}

// ---------------------------------------------------------------- prep A
__global__ __launch_bounds__(64) void k_prep_a(const float* __restrict__ seg,
                                               u16* __restrict__ ahi,
                                               u16* __restrict__ alo) {
  int row = blockIdx.x, lane = threadIdx.x;
  const float4* p = (const float4*)(seg + ((size_t)row << 9) + lane * 8);
  float4 a = p[0], b = p[1];
  float v[8] = {a.x, a.y, a.z, a.w, b.x, b.y, b.z, b.w};
  float s = 0.f;
#pragma unroll
  for (int i = 0; i < 8; ++i) s += v[i] * v[i];
#pragma unroll
  for (int m = 32; m; m >>= 1) s += __shfl_xor(s, m, 64);
  float nrm = sqrtf(s);
  u16 h[8], l[8];
#pragma unroll
  for (int i = 0; i < 8; ++i) split_bf(v[i] / nrm, h[i], l[i]);
  size_t off = ((size_t)row << 9) + lane * 8;
  *(uint4*)(ahi + off) = make_uint4(h[0] | (h[1] << 16), h[2] | (h[3] << 16),
                                    h[4] | (h[5] << 16), h[6] | (h[7] << 16));
  *(uint4*)(alo + off) = make_uint4(l[0] | (l[1] << 16), l[2] | (l[3] << 16),
                                    l[4] | (l[5] << 16), l[6] | (l[7] << 16));
}

// ---------------------------------------------------------------- transpose-split
__global__ __launch_bounds__(256) void k_tr(const float* __restrict__ src,
                                            u16* __restrict__ dh,
                                            u16* __restrict__ dl,
                                            int K, int N) {
  __shared__ u16 Th[64 * 66], Tl[64 * 66];
  int nb = blockIdx.x * 64, kb = blockIdx.y * 64;
  int tid = threadIdx.x;
#pragma unroll
  for (int i = 0; i < 16; ++i) {
    int e = tid + i * 256;
    int r = e >> 6, c = e & 63;
    float v = src[(size_t)(kb + r) * N + nb + c];
    u16 hi, lo; split_bf(v, hi, lo);
    Th[c * 66 + r] = hi;
    Tl[c * 66 + r] = lo;
  }
  __syncthreads();
#pragma unroll
  for (int i = 0; i < 16; ++i) {
    int e = tid + i * 256;
    int n = e >> 6, k = e & 63;
    dh[(size_t)(nb + n) * K + kb + k] = Th[n * 66 + k];
    if (dl) dl[(size_t)(nb + n) * K + kb + k] = Tl[n * 66 + k];
  }
}

// ---------------------------------------------------------------- S-GEMM (MFMA)
// block 64m x 256n, 4 waves each 64m x 64n. Async DMA staging into
// double-buffered unpadded LDS; one barrier per ks. 3-pass split bf16.
__global__ __launch_bounds__(256) void k_sgemm(const u16* __restrict__ ahi,
                                               const u16* __restrict__ alo,
                                               const u16* __restrict__ w1h,
                                               const u16* __restrict__ w1l,
                                               const float* __restrict__ b1,
                                               const float* __restrict__ W2,
                                               float* __restrict__ Spart) {
  __shared__ u16 Ah[2][64 * 32], Al_[2][64 * 32];   // 16 KB
  __shared__ u16 Wh[2][256 * 32], Wl[2][256 * 32];  // 64 KB  (total 80 KB)

  int tid = threadIdx.x;
  int wave = tid >> 6, lane = tid & 63, quad = lane >> 4, l15 = lane & 15;
  int b = blockIdx.z, mblk = blockIdx.y, nblk = blockIdx.x;
  int rowbase = b * NN + mblk * 64;
  int ncol0 = nblk * 256;
  int r_in = lane >> 2, c_in = lane & 3;   // DMA chunk coords

  f32x4 acc[4][4];
#pragma unroll
  for (int mi = 0; mi < 4; ++mi)
#pragma unroll
    for (int ni = 0; ni < 4; ++ni) acc[mi][ni] = (f32x4){0.f, 0.f, 0.f, 0.f};

  // --- staging lambda-equivalent (inlined twice): tile ks -> buffer tb
#define STAGE_TILE(ks_, tb_)                                                        \
  {                                                                                 \
    int k0_ = (ks_) * 32, half_ = k0_ >> 9, cb_ = k0_ & 511;                        \
    int grow_ = rowbase + wave * 16 + r_in + half_;                                 \
    if (grow_ > 32767) grow_ = 32767;                                               \
    size_t ga_ = (((size_t)grow_) << 9) + cb_ + c_in * 8;                           \
    dma16(ahi + ga_, &Ah [tb_][(wave * 16) * 32]);                                  \
    dma16(alo + ga_, &Al_[tb_][(wave * 16) * 32]);                                  \
    _Pragma("unroll")                                                               \
    for (int c_ = 0; c_ < 4; ++c_) {                                                \
      int n_ = wave * 64 + c_ * 16 + r_in;                                          \
      size_t gw_ = (size_t)(ncol0 + n_) * 1024 + k0_ + c_in * 8;                    \
      dma16(w1h + gw_, &Wh[tb_][(wave * 64 + c_ * 16) * 32]);                       \
      dma16(w1l + gw_, &Wl[tb_][(wave * 64 + c_ * 16) * 32]);                       \
    }                                                                               \
  }

  STAGE_TILE(0, 0)
  __syncthreads();                     // tile 0 ready

  for (int ks = 0; ks < 32; ++ks) {
    int bb = ks & 1;
    if (ks + 1 < 32) STAGE_TILE(ks + 1, bb ^ 1)   // async, overlaps compute

    bf16x8 a_h[4], a_l[4];
#pragma unroll
    for (int mi = 0; mi < 4; ++mi) {
      int off = (mi * 16 + l15) * 32 + quad * 8;
      a_h[mi] = *(const bf16x8*)&Ah [bb][off];
      a_l[mi] = *(const bf16x8*)&Al_[bb][off];
    }
#pragma unroll
    for (int ni = 0; ni < 4; ++ni) {
      int off = (wave * 64 + ni * 16 + l15) * 32 + quad * 8;
      bf16x8 b_h = *(const bf16x8*)&Wh[bb][off];
      bf16x8 b_l = *(const bf16x8*)&Wl[bb][off];
#pragma unroll
      for (int mi = 0; mi < 4; ++mi) {
        acc[mi][ni] = __builtin_amdgcn_mfma_f32_16x16x32_bf16(a_h[mi], b_h, acc[mi][ni], 0, 0, 0);
        acc[mi][ni] = __builtin_amdgcn_mfma_f32_16x16x32_bf16(a_h[mi], b_l, acc[mi][ni], 0, 0, 0);
        acc[mi][ni] = __builtin_amdgcn_mfma_f32_16x16x32_bf16(a_l[mi], b_h, acc[mi][ni], 0, 0, 0);
      }
    }
    __syncthreads();                   // drains DMA (next tile ready), frees bb
  }
#undef STAGE_TILE

  // epilogue: relu(acc + b1) . W2 over this wave's 64 cols; reduce, no atomics.
  // reuse Ah staging space (dead) as the cross-wave reduction buffer.
  float* red = (float*)Ah;             // 4 * 64 floats needed, 8 KB available
#pragma unroll
  for (int mi = 0; mi < 4; ++mi) {
#pragma unroll
    for (int reg = 0; reg < 4; ++reg) {
      float part = 0.f;
#pragma unroll
      for (int ni = 0; ni < 4; ++ni) {
        int n_g = ncol0 + wave * 64 + ni * 16 + l15;
        float h = acc[mi][ni][reg] + b1[n_g];
        h = h > 0.f ? h : 0.f;
        part = fmaf(h, W2[n_g], part);
      }
#pragma unroll
      for (int m = 8; m; m >>= 1) part += __shfl_xor(part, m, 64);
      if (l15 == 0) red[wave * 64 + mi * 16 + quad * 4 + reg] = part;
    }
  }
  __syncthreads();
  if (tid < 64) {
    float s = red[0 * 64 + tid] + red[1 * 64 + tid] + red[2 * 64 + tid] + red[3 * 64 + tid];
    int srow = mblk * 64 + tid;
    if (srow < NS)
      Spart[((size_t)nblk * BB + b) * NN + srow] = s;
  }
}

// ---------------------------------------------------------------- kernel 3
__global__ __launch_bounds__(256) void k_row(const float* __restrict__ S0,
                                             const float* __restrict__ S1,
                                             const float* __restrict__ mask,
                                             int* __restrict__ assign,
                                             float* __restrict__ weight,
                                             float* __restrict__ total,
                                             int* __restrict__ startn,
                                             int* __restrict__ endn) {
  int b = blockIdx.x, tid = threadIdx.x;
  __shared__ float Ssh[NS];
  __shared__ float Dsh[NS];
  __shared__ float tsh[NN];
  __shared__ float bsh[NN];
  __shared__ float totl[NN];
  __shared__ int   stl[NN];
  __shared__ int   enl[NN];
  __shared__ float red[256];

  for (int n = tid; n < NS; n += 256)
    Ssh[n] = S0[((size_t)b << 10) + n] + S1[((size_t)b << 10) + n];
  __syncthreads();

  float mn = INFINITY, mx = -INFINITY;
  for (int n = tid; n < NS; n += 256) {
    float v = Ssh[n];
    mn = fminf(mn, v); mx = fmaxf(mx, v);
  }
  red[tid] = mn; __syncthreads();
  for (int s = 128; s; s >>= 1) { if (tid < s) red[tid] = fminf(red[tid], red[tid + s]); __syncthreads(); }
  float Smin = red[0]; __syncthreads();
  red[tid] = mx; __syncthreads();
  for (int s = 128; s; s >>= 1) { if (tid < s) red[tid] = fmaxf(red[tid], red[tid + s]); __syncthreads(); }
  float Smax = red[0]; __syncthreads();

  for (int n = tid; n < NS; n += 256)
    Dsh[n] = 1.0f - (Ssh[n] - Smin) / (Smax - Smin);
  __syncthreads();

  for (int n = tid; n < NN; n += 256) {
    float P;
    if (n >= NS) {
      P = 0.f;
    } else {
      float D = Dsh[n];
      float fo, so;
      if (n == 0)            fo = fmaxf(D - Dsh[1], 0.f);
      else if (n >= NS - 2)  fo = fmaxf(D - Dsh[n - 2], 0.f);
      else                   fo = fminf(fmaxf(D - Dsh[n - 1], 0.f),
                                        fmaxf(D - Dsh[n + 1], 0.f));
      if (n <= 1)            so = fmaxf(D - Dsh[n + 2], 0.f);
      else if (n >= NS - 2)  so = 0.f;
      else                   so = fminf(fmaxf(D - Dsh[n - 2], 0.f),
                                        fmaxf(D - Dsh[n + 2], 0.f));
      P = fminf(fmaxf(fmaxf(fo, so) - 0.05f, 0.f), fo);
    }
    float m = mask[((size_t)b << 10) + n];
    P = P + (m - 1.0f);
    P = P > 0.f ? P : 0.f;
    float bs = tanhf(10.0f * P);
    float bh = tanhf(100000.0f * P);
    tsh[n] = bs + (bh - bs);
  }
  __syncthreads();

  if (tid == 0) {
    float acc = 0.f;
    for (int n = 0; n < NN; n += 8) {
      float t0 = tsh[n + 0], t1 = tsh[n + 1], t2 = tsh[n + 2], t3 = tsh[n + 3];
      float t4 = tsh[n + 4], t5 = tsh[n + 5], t6 = tsh[n + 6], t7 = tsh[n + 7];
      acc += t0; bsh[n + 0] = acc; acc += t1; bsh[n + 1] = acc;
      acc += t2; bsh[n + 2] = acc; acc += t3; bsh[n + 3] = acc;
      acc += t4; bsh[n + 4] = acc; acc += t5; bsh[n + 5] = acc;
      acc += t6; bsh[n + 6] = acc; acc += t7; bsh[n + 7] = acc;
    }
  }
  __syncthreads();

  float add1 = (bsh[0] == 0.0f) ? 1.0f : 0.0f;
  int   num  = (int)(bsh[NN - 1] + add1) + 1;

  for (int mi = tid; mi < NN; mi += 256) { totl[mi] = 0.f; stl[mi] = 1 << 30; enl[mi] = -1; }
  __syncthreads();

  for (int n = tid; n < NN; n += 256) {
    float bv = bsh[n] + add1;
    float kf = rintf(bv);
    int   k  = (int)kf;
    int   a  = -1; float w = 0.f;
    if (k >= 1 && k <= num && k <= NN) {
      float v = fabsf(kf - bv);
      w = 1.0f - tanhf(100000.0f * v);
      if (w > 0.f) {
        a = k - 1;
        atomicAdd(&totl[a], w);
        atomicMin(&stl[a], n);
        atomicMax(&enl[a], n);
      } else {
        a = -1; w = 0.f;
      }
    }
    assign[((size_t)b << 10) + n] = a;
    weight[((size_t)b << 10) + n] = w;
  }
  __syncthreads();
  for (int mi = tid; mi < NN; mi += 256) {
    total [((size_t)b << 10) + mi] = totl[mi];
    startn[((size_t)b << 10) + mi] = stl[mi];
    endn  [((size_t)b << 10) + mi] = enl[mi];
  }
}

// ---------------------------------------------------------------- kernel 4
__global__ __launch_bounds__(64) void k_pool(const float* __restrict__ seg,
                                             const int* __restrict__ assign,
                                             const float* __restrict__ weight,
                                             const float* __restrict__ total,
                                             const int* __restrict__ startn,
                                             const int* __restrict__ endn,
                                             float* __restrict__ wrep) {
  int bm = blockIdx.x;
  int b  = bm >> 10, m = bm & 1023;
  int lane = threadIdx.x;
  float acc[8] = {0.f, 0.f, 0.f, 0.f, 0.f, 0.f, 0.f, 0.f};
  float tm = total[bm];
  if (tm > 0.f) {
    int s = startn[bm], e = endn[bm];
    for (int n = s; n <= e; ++n) {
      if (assign[((size_t)b << 10) + n] != m) continue;
      float coef = weight[((size_t)b << 10) + n] / tm;
      const float4* p = (const float4*)(seg + (((size_t)b << 10) + n) * HH + lane * 8);
      float4 x = p[0], y = p[1];
      acc[0] = fmaf(coef, x.x, acc[0]); acc[1] = fmaf(coef, x.y, acc[1]);
      acc[2] = fmaf(coef, x.z, acc[2]); acc[3] = fmaf(coef, x.w, acc[3]);
      acc[4] = fmaf(coef, y.x, acc[4]); acc[5] = fmaf(coef, y.y, acc[5]);
      acc[6] = fmaf(coef, y.z, acc[6]); acc[7] = fmaf(coef, y.w, acc[7]);
    }
  }
  float4* dst = (float4*)(wrep + (size_t)bm * HH + lane * 8);
  dst[0] = make_float4(acc[0], acc[1], acc[2], acc[3]);
  dst[1] = make_float4(acc[4], acc[5], acc[6], acc[7]);
}

// ---------------------------------------------------------------- out MLP (MFMA bf16)
// block 64m x 512n, 8 waves (2m x 4n), wave tile 32m x 128n. W tiles via
// async DMA dbuf; A (fp32 wrep) converted via VGPR dbuf; Hid in LDS.
__global__ __launch_bounds__(512) void k_out(const u16* __restrict__ we1t,
                                             const u16* __restrict__ we2t,
                                             const float* __restrict__ be1,
                                             const float* __restrict__ be2,
                                             float* __restrict__ io) {
  __shared__ u16 Hid[64 * 520];        // 66.56 KB
  __shared__ u16 Wst[2][512 * 32];     // 64 KB
  __shared__ u16 Ast[2][64 * 32];      // 8 KB   (total ~139 KB)

  int tid = threadIdx.x;
  int wave = tid >> 6, lane = tid & 63, quad = lane >> 4, l15 = lane & 15;
  int wm = wave >> 2, wn = wave & 3;
  int rowbase = blockIdx.x * 64;
  int m_st = tid >> 3, ch_st = tid & 7;    // A staging: one float4 per thread
  int r_in = lane >> 2, c_in = lane & 3;   // W DMA chunk coords

#define STAGE_W(src_, ks_, tb_)                                                     \
  {                                                                                 \
    int k0_ = (ks_) * 32;                                                           \
    _Pragma("unroll")                                                               \
    for (int c_ = 0; c_ < 4; ++c_) {                                                \
      int n_ = wave * 64 + c_ * 16 + r_in;                                          \
      dma16(src_ + (size_t)n_ * 512 + k0_ + c_in * 8,                               \
            &Wst[tb_][(wave * 64 + c_ * 16) * 32]);                                 \
    }                                                                               \
  }

  f32x4 acc[2][8];
#pragma unroll
  for (int mi = 0; mi < 2; ++mi)
#pragma unroll
    for (int ni = 0; ni < 8; ++ni) acc[mi][ni] = (f32x4){0.f, 0.f, 0.f, 0.f};

  // prologue: A tile 0 (convert) + W tile 0 (DMA)
  {
    float4 v = *(const float4*)(io + (size_t)(rowbase + m_st) * HH + ch_st * 4);
    u32 p0 = f2bf(v.x) | ((u32)f2bf(v.y) << 16);
    u32 p1 = f2bf(v.z) | ((u32)f2bf(v.w) << 16);
    *(uint2*)&Ast[0][m_st * 32 + ch_st * 4] = make_uint2(p0, p1);
  }
  STAGE_W(we1t, 0, 0)
  __syncthreads();

  // ---- phase 1: hidden = relu(wrep @ We1 + be1)
  for (int ks = 0; ks < 16; ++ks) {
    int bb = ks & 1;
    bool have = (ks + 1) < 16;
    float4 nx;
    if (have) {
      STAGE_W(we1t, ks + 1, bb ^ 1)
      nx = *(const float4*)(io + (size_t)(rowbase + m_st) * HH + (ks + 1) * 32 + ch_st * 4);
    }
    bf16x8 a[2];
#pragma unroll
    for (int mi = 0; mi < 2; ++mi)
      a[mi] = *(const bf16x8*)&Ast[bb][(wm * 32 + mi * 16 + l15) * 32 + quad * 8];
#pragma unroll
    for (int ni = 0; ni < 8; ++ni) {
      bf16x8 bw = *(const bf16x8*)&Wst[bb][(wn * 128 + ni * 16 + l15) * 32 + quad * 8];
#pragma unroll
      for (int mi = 0; mi < 2; ++mi)
        acc[mi][ni] = __builtin_amdgcn_mfma_f32_16x16x32_bf16(a[mi], bw, acc[mi][ni], 0, 0, 0);
    }
    if (have) {
      u32 p0 = f2bf(nx.x) | ((u32)f2bf(nx.y) << 16);
      u32 p1 = f2bf(nx.z) | ((u32)f2bf(nx.w) << 16);
      *(uint2*)&Ast[bb ^ 1][m_st * 32 + ch_st * 4] = make_uint2(p0, p1);
    }
    __syncthreads();
  }
  // hidden -> LDS (bf16)
#pragma unroll
  for (int mi = 0; mi < 2; ++mi)
#pragma unroll
    for (int ni = 0; ni < 8; ++ni)
#pragma unroll
      for (int reg = 0; reg < 4; ++reg) {
        int n_g = wn * 128 + ni * 16 + l15;
        float h = acc[mi][ni][reg] + be1[n_g];
        h = h > 0.f ? h : 0.f;
        Hid[(wm * 32 + mi * 16 + quad * 4 + reg) * 520 + n_g] = f2bf(h);
      }

#pragma unroll
  for (int mi = 0; mi < 2; ++mi)
#pragma unroll
    for (int ni = 0; ni < 8; ++ni) acc[mi][ni] = (f32x4){0.f, 0.f, 0.f, 0.f};

  STAGE_W(we2t, 0, 0)
  __syncthreads();                      // Hid visible + W2 tile 0 ready

  // ---- phase 2: out = hidden @ We2 + be2
  for (int ks = 0; ks < 16; ++ks) {
    int bb = ks & 1;
    if (ks + 1 < 16) STAGE_W(we2t, ks + 1, bb ^ 1)
    int k0 = ks * 32;
    bf16x8 a[2];
#pragma unroll
    for (int mi = 0; mi < 2; ++mi)
      a[mi] = *(const bf16x8*)&Hid[(wm * 32 + mi * 16 + l15) * 520 + k0 + quad * 8];
#pragma unroll
    for (int ni = 0; ni < 8; ++ni) {
      bf16x8 bw = *(const bf16x8*)&Wst[bb][(wn * 128 + ni * 16 + l15) * 32 + quad * 8];
#pragma unroll
      for (int mi = 0; mi < 2; ++mi)
        acc[mi][ni] = __builtin_amdgcn_mfma_f32_16x16x32_bf16(a[mi], bw, acc[mi][ni], 0, 0, 0);
    }
    __syncthreads();
  }
#undef STAGE_W

  // epilogue: bias + (wrep == 0) mask, in-place f32 store (element-exclusive)
#pragma unroll
  for (int mi = 0; mi < 2; ++mi)
#pragma unroll
    for (int ni = 0; ni < 8; ++ni)
#pragma unroll
      for (int reg = 0; reg < 4; ++reg) {
        int n_g = wn * 128 + ni * 16 + l15;
        size_t row = (size_t)(rowbase + wm * 32 + mi * 16 + quad * 4 + reg);
        float o = acc[mi][ni][reg] + be2[n_g];
        float wr = io[row * HH + n_g];
        io[row * HH + n_g] = (wr == 0.f) ? 0.f : o;
      }
}

// ---------------------------------------------------------------- diag (hostcode only)
__global__ void k_diag(float* __restrict__ out, int hostcode) {
  if (hostcode != 0) out[0] = (float)hostcode;
}

// ---------------------------------------------------------------- launch
extern "C" void kernel_launch(void* const* d_in, const int* in_sizes, int n_in,
                              void* d_out, int out_size, void* d_ws, size_t ws_size,
                              hipStream_t stream) {
  const float* seg  = (const float*)d_in[0];
  const float* mask = (const float*)d_in[1];
  const float* W1   = (const float*)d_in[2];
  const float* b1   = (const float*)d_in[3];
  const float* W2   = (const float*)d_in[4];
  const float* We1  = (const float*)d_in[5];
  const float* be1  = (const float*)d_in[6];
  const float* We2  = (const float*)d_in[7];
  const float* be2  = (const float*)d_in[8];

  const size_t NROW = (size_t)BB * NN;            // 32768
  float* ws = (float*)d_ws;
  float* S0     = ws;                             // partial S, nblk=0
  float* S1     = S0 + NROW;                      // partial S, nblk=1
  int*   assign = (int*)(S1 + NROW);
  float* weight = (float*)(assign + NROW);
  float* total  = weight + NROW;
  int*   startn = (int*)(total + NROW);
  int*   endn   = startn + NROW;
  u16*   w1h    = (u16*)(endn + NROW);            // [n=512][k=1024]
  u16*   w1l    = w1h + (size_t)512 * 1024;
  u16*   we1t   = w1l + (size_t)512 * 1024;       // [n=512][k=512]
  u16*   we2t   = we1t + (size_t)512 * 512;       // end ~4.8 MB

  float* out = (float*)d_out;
  u16*   ahi = (u16*)d_out;                       // A hi plane (33.5 MB)
  u16*   alo = ahi + (size_t)NROW * HH;           // A lo plane (33.5 MB)

  int hostcode = 0;
  if (ws_size < (size_t)7 * NROW * 4 + (size_t)3 * 1024 * 1024) hostcode += 32768;
  if (out_size != 16777216) hostcode += 8192;

  k_prep_a<<<dim3(BB * NN), dim3(64), 0, stream>>>(seg, ahi, alo);
  k_tr    <<<dim3(8, 16), dim3(256), 0, stream>>>(W1, w1h, w1l, 1024, 512);
  k_tr    <<<dim3(8, 8),  dim3(256), 0, stream>>>(We1, we1t, (u16*)nullptr, 512, 512);
  k_tr    <<<dim3(8, 8),  dim3(256), 0, stream>>>(We2, we2t, (u16*)nullptr, 512, 512);
  k_sgemm <<<dim3(2, 16, BB), dim3(256), 0, stream>>>(ahi, alo, w1h, w1l, b1, W2, S0);
  k_row   <<<dim3(BB), dim3(256), 0, stream>>>(S0, S1, mask, assign, weight, total, startn, endn);
  k_pool  <<<dim3(BB * NN), dim3(64), 0, stream>>>(seg, assign, weight, total, startn, endn, out);
  k_out   <<<dim3(NROW / 64), dim3(512), 0, stream>>>(we1t, we2t, be1, be2, out);
  k_diag  <<<dim3(1), dim3(1), 0, stream>>>(out, hostcode);
}